// Round 7
// baseline (405.688 us; speedup 1.0000x reference)
//
#include <hip/hip_runtime.h>
#include <hip/hip_bf16.h>
#include <math.h>

// Problem: CausalSelfAttention  B=4 T=2048 D=1024 H=16 HD=64
// d_in: fp32 x[4,2048,1024], Wq,Wk,Wv,Wp[1024,1024], bp[1024]; d_out: fp32 y.
// Pipeline: cvt(fp32->bf16 into ws) -> qkv -> attn -> proj.
// V stored TRANSPOSED [B,H,HD,T]; attn uses KVBLK=64 so V^T reads are full
// 128B line segments. attn grid: x = bh (fast; XCD-L2 panel residency),
// y = 32 q-tiles in LPT order. Single-buffer reload pipeline (VGPR <= 128).

#define B_  4
#define T_  2048
#define D_  1024
#define H_  16
#define HD_ 64
#define M_  (B_ * T_)   // 8192 rows

typedef short bf16x8 __attribute__((ext_vector_type(8)));
typedef float f32x4  __attribute__((ext_vector_type(4)));

__device__ __forceinline__ f32x4 mfma16(bf16x8 a, bf16x8 b, f32x4 c) {
    return __builtin_amdgcn_mfma_f32_16x16x32_bf16(a, b, c, 0, 0, 0);
}

__device__ __forceinline__ void gl_lds16(const unsigned short* g, unsigned short* l) {
    __builtin_amdgcn_global_load_lds(
        (const __attribute__((address_space(1))) void*)g,
        (__attribute__((address_space(3))) void*)l, 16, 0, 0);
}

__device__ __forceinline__ unsigned short f2bf(float f) {
    union { __hip_bfloat16 h; unsigned short u; } cv;
    cv.h = __float2bfloat16(f);
    return cv.u;
}
__device__ __forceinline__ float bf2f(unsigned short u) {
    return __uint_as_float(((unsigned)u) << 16);
}
__device__ __forceinline__ float exp2_fast(float x) {
    return __builtin_amdgcn_exp2f(x);   // v_exp_f32: 2^x
}

struct su4 { unsigned short x, y, z, w; };

// ---------------------------------------------------------------------------
__global__ __launch_bounds__(256)
void cvt_kernel(const float* __restrict__ in, unsigned short* __restrict__ out) {
    const int i = blockIdx.x * 256 + threadIdx.x;
    const float4 v = ((const float4*)in)[i];
    su4 o;
    o.x = f2bf(v.x); o.y = f2bf(v.y); o.z = f2bf(v.z); o.w = f2bf(v.w);
    ((su4*)out)[i] = o;
}

__global__ __launch_bounds__(256)
void cvtw_kernel(const float* __restrict__ w0, const float* __restrict__ w1,
                 const float* __restrict__ w2, const float* __restrict__ w3,
                 unsigned short* __restrict__ o0, unsigned short* __restrict__ o1,
                 unsigned short* __restrict__ o2, unsigned short* __restrict__ o3) {
    const int y = blockIdx.y;
    const float* in       = (y == 0) ? w0 : (y == 1) ? w1 : (y == 2) ? w2 : w3;
    unsigned short* out   = (y == 0) ? o0 : (y == 1) ? o1 : (y == 2) ? o2 : o3;
    const int i = blockIdx.x * 256 + threadIdx.x;
    const float4 v = ((const float4*)in)[i];
    su4 o;
    o.x = f2bf(v.x); o.y = f2bf(v.y); o.z = f2bf(v.z); o.w = f2bf(v.w);
    ((su4*)out)[i] = o;
}

// ---------------------------------------------------------------------------
// Fused QKV GEMM: C = X @ W^T.  Q,K scattered to [B,H,T,HD]; V to [B,H,HD,T]
// via operand-swapped MFMA (acc holds C^T for the V section).
// ---------------------------------------------------------------------------
__global__ __launch_bounds__(256, 2)
void qkv_kernel(const unsigned short* __restrict__ X,
                const unsigned short* __restrict__ Wq,
                const unsigned short* __restrict__ Wk,
                const unsigned short* __restrict__ Wv,
                unsigned short* __restrict__ Qo,
                unsigned short* __restrict__ Ko,
                unsigned short* __restrict__ Vo)
{
    __shared__ unsigned short As[128 * 64];
    __shared__ unsigned short Bs[128 * 64];

    const int m0 = blockIdx.x * 128;
    const int by = blockIdx.y;
    const unsigned short* W = (by < 8) ? Wq : (by < 16) ? Wk : Wv;
    unsigned short*       O = (by < 8) ? Qo : (by < 16) ? Ko : Vo;
    const int n0   = (by & 7) * 128;
    const bool vsec = (by >= 16);
    const int tid  = threadIdx.x;
    const int lane = tid & 63;
    const int wv   = tid >> 6;
    const int wr   = (wv >> 1) * 64;
    const int wc   = (wv & 1) * 64;
    const int g    = lane >> 4;
    const int c    = lane & 15;

    f32x4 acc[4][4] = {};

    for (int k0 = 0; k0 < D_; k0 += 64) {
        #pragma unroll
        for (int i = 0; i < 4; ++i) {
            const int flat = i * 2048 + tid * 8;
            const int row = flat >> 6, col = flat & 63;
            gl_lds16(X + (size_t)(m0 + row) * D_ + k0 + col, As + flat);
            gl_lds16(W + (size_t)(n0 + row) * D_ + k0 + col, Bs + flat);
        }
        __syncthreads();
        #pragma unroll
        for (int kk = 0; kk < 64; kk += 32) {
            bf16x8 af[4], bg[4];
            #pragma unroll
            for (int mi = 0; mi < 4; ++mi)
                af[mi] = *(const bf16x8*)(As + (wr + mi * 16 + c) * 64 + kk + g * 8);
            #pragma unroll
            for (int ni = 0; ni < 4; ++ni)
                bg[ni] = *(const bf16x8*)(Bs + (wc + ni * 16 + c) * 64 + kk + g * 8);
            if (!vsec) {
                #pragma unroll
                for (int mi = 0; mi < 4; ++mi)
                    #pragma unroll
                    for (int ni = 0; ni < 4; ++ni)
                        acc[mi][ni] = mfma16(af[mi], bg[ni], acc[mi][ni]);
            } else {
                #pragma unroll
                for (int mi = 0; mi < 4; ++mi)
                    #pragma unroll
                    for (int ni = 0; ni < 4; ++ni)
                        acc[mi][ni] = mfma16(bg[ni], af[mi], acc[mi][ni]);
            }
        }
        __syncthreads();
    }

    if (!vsec) {
        #pragma unroll
        for (int mi = 0; mi < 4; ++mi)
            #pragma unroll
            for (int ni = 0; ni < 4; ++ni)
                #pragma unroll
                for (int r = 0; r < 4; ++r) {
                    const int m = m0 + wr + mi * 16 + g * 4 + r;
                    const int n = n0 + wc + ni * 16 + c;
                    const int b = m >> 11, t = m & (T_ - 1);
                    const int h = n >> 6,  hd = n & 63;
                    O[((size_t)((b << 4) + h) * T_ + t) * HD_ + hd] = f2bf(acc[mi][ni][r]);
                }
    } else {
        #pragma unroll
        for (int mi = 0; mi < 4; ++mi)
            #pragma unroll
            for (int ni = 0; ni < 4; ++ni)
                #pragma unroll
                for (int r = 0; r < 4; ++r) {
                    const int n = n0 + wc + ni * 16 + g * 4 + r;
                    const int m = m0 + wr + mi * 16 + c;
                    const int b = m >> 11, t = m & (T_ - 1);
                    const int h = n >> 6,  hd = n & 63;
                    O[((size_t)((b << 4) + h) * HD_ + hd) * T_ + t] = f2bf(acc[mi][ni][r]);
                }
    }
}

// ---------------------------------------------------------------------------
// P-transpose helper (verified lane math): given 2x4 P values (k-local rows
// ni*16+g*4+r, q col = c) produce the PV A-operand fragment for one 32-key
// subtile: lane (c,g) gets k = g*8+j pairs.
// ---------------------------------------------------------------------------
__device__ __forceinline__ bf16x8 ptrans(const float p0[4], const float p1[4],
                                         int lane, int g, int c) {
    unsigned int P32[2][2];
    P32[0][0] = (unsigned int)f2bf(p0[0]) | ((unsigned int)f2bf(p0[1]) << 16);
    P32[0][1] = (unsigned int)f2bf(p0[2]) | ((unsigned int)f2bf(p0[3]) << 16);
    P32[1][0] = (unsigned int)f2bf(p1[0]) | ((unsigned int)f2bf(p1[1]) << 16);
    P32[1][1] = (unsigned int)f2bf(p1[2]) | ((unsigned int)f2bf(p1[3]) << 16);
    const int sl0 = c + ((lane & 16) << 1);
    const int sl1 = sl0 + 16;
    const int q00 = __shfl((int)P32[0][0], sl0), q10 = __shfl((int)P32[1][0], sl0);
    const int q01 = __shfl((int)P32[0][1], sl0), q11 = __shfl((int)P32[1][1], sl0);
    const int q02 = __shfl((int)P32[0][0], sl1), q12 = __shfl((int)P32[1][0], sl1);
    const int q03 = __shfl((int)P32[0][1], sl1), q13 = __shfl((int)P32[1][1], sl1);
    const bool nhi = (g & 2) != 0;
    union { unsigned int u[4]; bf16x8 v; } pf;
    pf.u[0] = nhi ? q10 : q00;
    pf.u[1] = nhi ? q11 : q01;
    pf.u[2] = nhi ? q12 : q02;
    pf.u[3] = nhi ? q13 : q03;
    return pf.v;
}

// ---------------------------------------------------------------------------
// Causal flash attention v5: KVBLK=64, single-buffer reload pipeline,
// LPT grid (bh fast axis), no LDS, no barriers.
// ---------------------------------------------------------------------------
__global__ __launch_bounds__(256, 4)
void attn_kernel(const unsigned short* __restrict__ Q,
                 const unsigned short* __restrict__ K,
                 const unsigned short* __restrict__ VT,
                 unsigned short* __restrict__ Y)
{
    const int bh = blockIdx.x;          // fast axis -> XCD panel residency
    const int qt = 31 - blockIdx.y;     // LPT: heaviest q-tiles first
    const unsigned short* Qp  = Q  + (size_t)bh * T_ * HD_;
    const unsigned short* Kp  = K  + (size_t)bh * T_ * HD_;
    const unsigned short* VTp = VT + (size_t)bh * HD_ * T_;
    const int b = bh >> 4, h = bh & 15;

    const int lane = threadIdx.x & 63;
    const int w    = threadIdx.x >> 6;
    const int g    = lane >> 4;
    const int c    = lane & 15;
    const float SC = 0.18033688011112042f;   // (1/sqrt(64)) * log2(e)

    const int qw = qt * 64 + w * 16;

    // Q as B-operand frags, pre-scaled (softmax scale folded, log2 domain)
    bf16x8 qf[2];
    #pragma unroll
    for (int dk = 0; dk < 2; ++dk) {
        bf16x8 t = *(const bf16x8*)(Qp + (size_t)(qw + c) * HD_ + dk * 32 + g * 8);
        #pragma unroll
        for (int j = 0; j < 8; ++j)
            t[j] = (short)f2bf(bf2f((unsigned short)t[j]) * SC);
        qf[dk] = t;
    }

    float m_l = -1e30f, l_l = 0.f;
    f32x4 oacc[4] = {};

    bf16x8 kf[8], vf[8];                // kf[s*4+ni*2+dk], vf[s*4+dn]
    auto loadK64 = [&](int tb) {
        #pragma unroll
        for (int s = 0; s < 2; ++s)
            #pragma unroll
            for (int ni = 0; ni < 2; ++ni)
                #pragma unroll
                for (int dk = 0; dk < 2; ++dk)
                    kf[s * 4 + ni * 2 + dk] = *(const bf16x8*)
                        (Kp + (size_t)(tb + s * 32 + ni * 16 + c) * HD_ + dk * 32 + g * 8);
    };
    auto loadV64 = [&](int tb) {
        #pragma unroll
        for (int s = 0; s < 2; ++s)
            #pragma unroll
            for (int dn = 0; dn < 4; ++dn)
                vf[s * 4 + dn] = *(const bf16x8*)
                    (VTp + (size_t)(dn * 16 + c) * T_ + tb + s * 32 + g * 8);
    };

    loadK64(0);
    loadV64(0);
    const int nt = qt + 1;              // 64-key tiles (last is diagonal)

    for (int ti = 0; ti < nt; ++ti) {
        const int tb = ti << 6;
        const bool last = (ti == nt - 1);

        // QK^T (swapped): s[sub][ni] holds S[tb+sub*32+ni*16+g*4+r][qw+c]
        f32x4 sA[2] = {}, sB[2] = {};
        #pragma unroll
        for (int ni = 0; ni < 2; ++ni)
            #pragma unroll
            for (int dk = 0; dk < 2; ++dk) {
                sA[ni] = mfma16(kf[ni * 2 + dk],     qf[dk], sA[ni]);
                sB[ni] = mfma16(kf[4 + ni * 2 + dk], qf[dk], sB[ni]);
            }
        // reload K for next tile (WAR after QK consumed kf)
        if (!last) loadK64(tb + 64);

        // mask (diagonal tile only) in place
        if (last) {
            #pragma unroll
            for (int ni = 0; ni < 2; ++ni)
                #pragma unroll
                for (int r = 0; r < 4; ++r) {
                    const int kA = tb + ni * 16 + g * 4 + r;
                    sA[ni][r] = (kA      <= qw + c) ? sA[ni][r] : -1e30f;
                    sB[ni][r] = (kA + 32 <= qw + c) ? sB[ni][r] : -1e30f;
                }
        }

        // online softmax over 16 values + 2 shuffles
        float pmax = sA[0][0];
        #pragma unroll
        for (int ni = 0; ni < 2; ++ni)
            #pragma unroll
            for (int r = 0; r < 4; ++r) {
                pmax = fmaxf(pmax, sA[ni][r]);
                pmax = fmaxf(pmax, sB[ni][r]);
            }
        pmax = fmaxf(pmax, __shfl_xor(pmax, 16));
        pmax = fmaxf(pmax, __shfl_xor(pmax, 32));

        const float mn = fmaxf(m_l, pmax);
        const float al = exp2_fast(m_l - mn);
        m_l = mn;

        float rs = 0.f;
        #pragma unroll
        for (int ni = 0; ni < 2; ++ni)
            #pragma unroll
            for (int r = 0; r < 4; ++r) {
                const float eA = exp2_fast(sA[ni][r] - mn);
                const float eB = exp2_fast(sB[ni][r] - mn);
                sA[ni][r] = eA; sB[ni][r] = eB;
                rs += eA + eB;
            }
        rs += __shfl_xor(rs, 16);
        rs += __shfl_xor(rs, 32);
        l_l = l_l * al + rs;

        // pack + transpose per subtile
        float pA0[4] = {sA[0][0], sA[0][1], sA[0][2], sA[0][3]};
        float pA1[4] = {sA[1][0], sA[1][1], sA[1][2], sA[1][3]};
        float pB0[4] = {sB[0][0], sB[0][1], sB[0][2], sB[0][3]};
        float pB1[4] = {sB[1][0], sB[1][1], sB[1][2], sB[1][3]};
        const bf16x8 pfA = ptrans(pA0, pA1, lane, g, c);
        const bf16x8 pfB = ptrans(pB0, pB1, lane, g, c);

        // rescale + PV (swapped): oacc rows = d, col = q = c
        #pragma unroll
        for (int dn = 0; dn < 4; ++dn) {
            #pragma unroll
            for (int r = 0; r < 4; ++r)
                oacc[dn][r] *= al;
            oacc[dn] = mfma16(vf[dn],     pfA, oacc[dn]);
            oacc[dn] = mfma16(vf[4 + dn], pfB, oacc[dn]);
        }
        // reload V for next tile (WAR after PV consumed vf)
        if (!last) loadV64(tb + 64);
    }

    // Epilogue: O[q = qw+c][d = dn*16 + g*4 + r], packed 8B stores
    const float li = 1.f / l_l;
    const size_t rowoff = (size_t)(b * T_ + qw + c) * D_ + h * 64;
    #pragma unroll
    for (int dn = 0; dn < 4; ++dn) {
        const unsigned int u0 = (unsigned int)f2bf(oacc[dn][0] * li)
                              | ((unsigned int)f2bf(oacc[dn][1] * li) << 16);
        const unsigned int u1 = (unsigned int)f2bf(oacc[dn][2] * li)
                              | ((unsigned int)f2bf(oacc[dn][3] * li) << 16);
        uint2 st; st.x = u0; st.y = u1;
        *(uint2*)(Y + rowoff + dn * 16 + g * 4) = st;
    }
}

// ---------------------------------------------------------------------------
// Output projection:  out = Y @ Wp^T + bp.  Y bf16[8192,1024]; out fp32.
// ---------------------------------------------------------------------------
__global__ __launch_bounds__(256, 2)
void proj_kernel(const unsigned short* __restrict__ Yin,
                 const unsigned short* __restrict__ Wp,
                 const float* __restrict__ bp,
                 float* __restrict__ Out)
{
    __shared__ unsigned short As[128 * 64];
    __shared__ unsigned short Bs[128 * 64];

    const int m0 = blockIdx.x * 128;
    const int n0 = blockIdx.y * 128;
    const int tid  = threadIdx.x;
    const int lane = tid & 63;
    const int wv   = tid >> 6;
    const int wr   = (wv >> 1) * 64;
    const int wc   = (wv & 1) * 64;
    const int g    = lane >> 4;
    const int c    = lane & 15;

    f32x4 acc[4][4] = {};

    for (int k0 = 0; k0 < D_; k0 += 64) {
        #pragma unroll
        for (int i = 0; i < 4; ++i) {
            const int flat = i * 2048 + tid * 8;
            const int row = flat >> 6, col = flat & 63;
            gl_lds16(Yin + (size_t)(m0 + row) * D_ + k0 + col, As + flat);
            gl_lds16(Wp  + (size_t)(n0 + row) * D_ + k0 + col, Bs + flat);
        }
        __syncthreads();
        #pragma unroll
        for (int kk = 0; kk < 64; kk += 32) {
            bf16x8 af[4], bg[4];
            #pragma unroll
            for (int mi = 0; mi < 4; ++mi)
                af[mi] = *(const bf16x8*)(As + (wr + mi * 16 + c) * 64 + kk + g * 8);
            #pragma unroll
            for (int ni = 0; ni < 4; ++ni)
                bg[ni] = *(const bf16x8*)(Bs + (wc + ni * 16 + c) * 64 + kk + g * 8);
            #pragma unroll
            for (int mi = 0; mi < 4; ++mi)
                #pragma unroll
                for (int ni = 0; ni < 4; ++ni)
                    acc[mi][ni] = mfma16(af[mi], bg[ni], acc[mi][ni]);
        }
        __syncthreads();
    }

    #pragma unroll
    for (int mi = 0; mi < 4; ++mi) {
        #pragma unroll
        for (int ni = 0; ni < 4; ++ni) {
            const int n = n0 + wc + ni * 16 + c;
            const float bb = bp[n];
            #pragma unroll
            for (int r = 0; r < 4; ++r) {
                const int m = m0 + wr + mi * 16 + g * 4 + r;
                Out[(size_t)m * D_ + n] = acc[mi][ni][r] + bb;
            }
        }
    }
}

// ---------------------------------------------------------------------------
extern "C" void kernel_launch(void* const* d_in, const int* in_sizes, int n_in,
                              void* d_out, int out_size, void* d_ws, size_t ws_size,
                              hipStream_t stream) {
    const float* x  = (const float*)d_in[0];
    const float* Wq = (const float*)d_in[1];
    const float* Wk = (const float*)d_in[2];
    const float* Wv = (const float*)d_in[3];
    const float* Wp = (const float*)d_in[4];
    const float* bp = (const float*)d_in[5];
    float* out = (float*)d_out;

    const size_t SZ  = (size_t)M_ * D_;      // 8388608
    const size_t WSZ = (size_t)D_ * D_;      // 1048576
    unsigned short* ws = (unsigned short*)d_ws;
    unsigned short* XB  = ws;                 // also Y after qkv
    unsigned short* WQB = XB  + SZ;
    unsigned short* WKB = WQB + WSZ;
    unsigned short* WVB = WKB + WSZ;
    unsigned short* WPB = WVB + WSZ;
    unsigned short* Qw  = WPB + WSZ;
    unsigned short* Kw  = Qw + SZ;
    unsigned short* Vw  = Kw + SZ;            // V^T [B,H,HD,T]
    unsigned short* Yw  = XB;                 // overlay: x_bf16 dead after qkv

    dim3 blk(256);
    cvt_kernel <<<dim3(SZ / 1024),     blk, 0, stream>>>(x, XB);
    cvtw_kernel<<<dim3(WSZ / 1024, 4), blk, 0, stream>>>(Wq, Wk, Wv, Wp, WQB, WKB, WVB, WPB);

    qkv_kernel <<<dim3(M_ / 128, 24), blk, 0, stream>>>(XB, WQB, WKB, WVB, Qw, Kw, Vw);
    attn_kernel<<<dim3(B_ * H_, 32), blk, 0, stream>>>(Qw, Kw, Vw, Yw);
    proj_kernel<<<dim3(M_ / 128, D_ / 128), blk, 0, stream>>>(Yw, WPB, bp, out);
}

// Round 8
// 208.447 us; speedup vs baseline: 1.9462x; 1.9462x over previous
//
#include <hip/hip_runtime.h>
#include <hip/hip_bf16.h>
#include <math.h>

// Problem: CausalSelfAttention  B=4 T=2048 D=1024 H=16 HD=64
// d_in: fp32 x[4,2048,1024], Wq,Wk,Wv,Wp[1024,1024], bp[1024]; d_out: fp32 y.
// Pipeline: cvt(fp32->bf16 into ws) -> qkv -> attn -> proj.
// V stored TRANSPOSED [B,H,HD,T]. attn: m97-style LDS staging (K+V tile
// shared by 4 waves, single-buffer stage/barrier/compute/barrier), XOR-
// swizzled LDS (linear gl_lds dest + pre-swizzled global src + swizzled
// read: rule both-sides-or-neither). Grid: bh fast axis (XCD panel
// residency) x causal-paired q-tiles (uniform work).

#define B_  4
#define T_  2048
#define D_  1024
#define H_  16
#define HD_ 64
#define M_  (B_ * T_)   // 8192 rows

typedef short bf16x8 __attribute__((ext_vector_type(8)));
typedef float f32x4  __attribute__((ext_vector_type(4)));

__device__ __forceinline__ f32x4 mfma16(bf16x8 a, bf16x8 b, f32x4 c) {
    return __builtin_amdgcn_mfma_f32_16x16x32_bf16(a, b, c, 0, 0, 0);
}

__device__ __forceinline__ void gl_lds16(const unsigned short* g, unsigned short* l) {
    __builtin_amdgcn_global_load_lds(
        (const __attribute__((address_space(1))) void*)g,
        (__attribute__((address_space(3))) void*)l, 16, 0, 0);
}

__device__ __forceinline__ unsigned short f2bf(float f) {
    union { __hip_bfloat16 h; unsigned short u; } cv;
    cv.h = __float2bfloat16(f);
    return cv.u;
}
__device__ __forceinline__ float bf2f(unsigned short u) {
    return __uint_as_float(((unsigned)u) << 16);
}
__device__ __forceinline__ float exp2_fast(float x) {
    return __builtin_amdgcn_exp2f(x);   // v_exp_f32: 2^x
}

struct su4 { unsigned short x, y, z, w; };

// ---------------------------------------------------------------------------
__global__ __launch_bounds__(256)
void cvt_kernel(const float* __restrict__ in, unsigned short* __restrict__ out) {
    const int i = blockIdx.x * 256 + threadIdx.x;
    const float4 v = ((const float4*)in)[i];
    su4 o;
    o.x = f2bf(v.x); o.y = f2bf(v.y); o.z = f2bf(v.z); o.w = f2bf(v.w);
    ((su4*)out)[i] = o;
}

__global__ __launch_bounds__(256)
void cvtw_kernel(const float* __restrict__ w0, const float* __restrict__ w1,
                 const float* __restrict__ w2, const float* __restrict__ w3,
                 unsigned short* __restrict__ o0, unsigned short* __restrict__ o1,
                 unsigned short* __restrict__ o2, unsigned short* __restrict__ o3) {
    const int y = blockIdx.y;
    const float* in       = (y == 0) ? w0 : (y == 1) ? w1 : (y == 2) ? w2 : w3;
    unsigned short* out   = (y == 0) ? o0 : (y == 1) ? o1 : (y == 2) ? o2 : o3;
    const int i = blockIdx.x * 256 + threadIdx.x;
    const float4 v = ((const float4*)in)[i];
    su4 o;
    o.x = f2bf(v.x); o.y = f2bf(v.y); o.z = f2bf(v.z); o.w = f2bf(v.w);
    ((su4*)out)[i] = o;
}

// ---------------------------------------------------------------------------
// Fused QKV GEMM: C = X @ W^T.  Q,K scattered to [B,H,T,HD]; V to [B,H,HD,T]
// via operand-swapped MFMA (acc holds C^T for the V section).
// ---------------------------------------------------------------------------
__global__ __launch_bounds__(256, 2)
void qkv_kernel(const unsigned short* __restrict__ X,
                const unsigned short* __restrict__ Wq,
                const unsigned short* __restrict__ Wk,
                const unsigned short* __restrict__ Wv,
                unsigned short* __restrict__ Qo,
                unsigned short* __restrict__ Ko,
                unsigned short* __restrict__ Vo)
{
    __shared__ unsigned short As[128 * 64];
    __shared__ unsigned short Bs[128 * 64];

    const int m0 = blockIdx.x * 128;
    const int by = blockIdx.y;
    const unsigned short* W = (by < 8) ? Wq : (by < 16) ? Wk : Wv;
    unsigned short*       O = (by < 8) ? Qo : (by < 16) ? Ko : Vo;
    const int n0   = (by & 7) * 128;
    const bool vsec = (by >= 16);
    const int tid  = threadIdx.x;
    const int lane = tid & 63;
    const int wv   = tid >> 6;
    const int wr   = (wv >> 1) * 64;
    const int wc   = (wv & 1) * 64;
    const int g    = lane >> 4;
    const int c    = lane & 15;

    f32x4 acc[4][4] = {};

    for (int k0 = 0; k0 < D_; k0 += 64) {
        #pragma unroll
        for (int i = 0; i < 4; ++i) {
            const int flat = i * 2048 + tid * 8;
            const int row = flat >> 6, col = flat & 63;
            gl_lds16(X + (size_t)(m0 + row) * D_ + k0 + col, As + flat);
            gl_lds16(W + (size_t)(n0 + row) * D_ + k0 + col, Bs + flat);
        }
        __syncthreads();
        #pragma unroll
        for (int kk = 0; kk < 64; kk += 32) {
            bf16x8 af[4], bg[4];
            #pragma unroll
            for (int mi = 0; mi < 4; ++mi)
                af[mi] = *(const bf16x8*)(As + (wr + mi * 16 + c) * 64 + kk + g * 8);
            #pragma unroll
            for (int ni = 0; ni < 4; ++ni)
                bg[ni] = *(const bf16x8*)(Bs + (wc + ni * 16 + c) * 64 + kk + g * 8);
            if (!vsec) {
                #pragma unroll
                for (int mi = 0; mi < 4; ++mi)
                    #pragma unroll
                    for (int ni = 0; ni < 4; ++ni)
                        acc[mi][ni] = mfma16(af[mi], bg[ni], acc[mi][ni]);
            } else {
                #pragma unroll
                for (int mi = 0; mi < 4; ++mi)
                    #pragma unroll
                    for (int ni = 0; ni < 4; ++ni)
                        acc[mi][ni] = mfma16(bg[ni], af[mi], acc[mi][ni]);
            }
        }
        __syncthreads();
    }

    if (!vsec) {
        #pragma unroll
        for (int mi = 0; mi < 4; ++mi)
            #pragma unroll
            for (int ni = 0; ni < 4; ++ni)
                #pragma unroll
                for (int r = 0; r < 4; ++r) {
                    const int m = m0 + wr + mi * 16 + g * 4 + r;
                    const int n = n0 + wc + ni * 16 + c;
                    const int b = m >> 11, t = m & (T_ - 1);
                    const int h = n >> 6,  hd = n & 63;
                    O[((size_t)((b << 4) + h) * T_ + t) * HD_ + hd] = f2bf(acc[mi][ni][r]);
                }
    } else {
        #pragma unroll
        for (int mi = 0; mi < 4; ++mi)
            #pragma unroll
            for (int ni = 0; ni < 4; ++ni)
                #pragma unroll
                for (int r = 0; r < 4; ++r) {
                    const int n = n0 + wc + ni * 16 + g * 4 + r;
                    const int m = m0 + wr + mi * 16 + c;
                    const int b = m >> 11, t = m & (T_ - 1);
                    const int h = n >> 6,  hd = n & 63;
                    O[((size_t)((b << 4) + h) * HD_ + hd) * T_ + t] = f2bf(acc[mi][ni][r]);
                }
    }
}

// ---------------------------------------------------------------------------
// P-transpose helper (verified lane math).
// ---------------------------------------------------------------------------
__device__ __forceinline__ bf16x8 ptrans(const f32x4& p0, const f32x4& p1,
                                         int lane, int g, int c) {
    unsigned int P32[2][2];
    P32[0][0] = (unsigned int)f2bf(p0[0]) | ((unsigned int)f2bf(p0[1]) << 16);
    P32[0][1] = (unsigned int)f2bf(p0[2]) | ((unsigned int)f2bf(p0[3]) << 16);
    P32[1][0] = (unsigned int)f2bf(p1[0]) | ((unsigned int)f2bf(p1[1]) << 16);
    P32[1][1] = (unsigned int)f2bf(p1[2]) | ((unsigned int)f2bf(p1[3]) << 16);
    const int sl0 = c + ((lane & 16) << 1);
    const int sl1 = sl0 + 16;
    const int q00 = __shfl((int)P32[0][0], sl0), q10 = __shfl((int)P32[1][0], sl0);
    const int q01 = __shfl((int)P32[0][1], sl0), q11 = __shfl((int)P32[1][1], sl0);
    const int q02 = __shfl((int)P32[0][0], sl1), q12 = __shfl((int)P32[1][0], sl1);
    const int q03 = __shfl((int)P32[0][1], sl1), q13 = __shfl((int)P32[1][1], sl1);
    const bool nhi = (g & 2) != 0;
    union { unsigned int u[4]; bf16x8 v; } pf;
    pf.u[0] = nhi ? q10 : q00;
    pf.u[1] = nhi ? q11 : q01;
    pf.u[2] = nhi ? q12 : q02;
    pf.u[3] = nhi ? q13 : q03;
    return pf.v;
}

// ---------------------------------------------------------------------------
// Causal flash attention v6: LDS-staged K/V shared by 4 waves (m97 loop),
// XOR-swizzled LDS, KVBLK=64, causal pairing, bh-fast grid.
// LDS: K tile [64][64] bf16 (8KB) + V^T tile [64][64] (8KB) = 16KB.
// Swizzle: phys_byte = row*128 + (log_byte ^ ((row&3)<<5)); staged via
// linear gl_lds dest + pre-swizzled global source (involution).
// ---------------------------------------------------------------------------
__global__ __launch_bounds__(256, 4)
void attn_kernel(const unsigned short* __restrict__ Q,
                 const unsigned short* __restrict__ K,
                 const unsigned short* __restrict__ VT,
                 unsigned short* __restrict__ Y)
{
    __shared__ unsigned short Ks[4096];   // K tile, swizzled
    __shared__ unsigned short Vs[4096];   // V^T tile, swizzled

    const int bh = blockIdx.x;          // fast axis -> XCD panel residency
    const int pr = blockIdx.y;          // 0..15, paired with 31-pr
    const unsigned short* Qp  = Q  + (size_t)bh * T_ * HD_;
    const unsigned short* Kp  = K  + (size_t)bh * T_ * HD_;
    const unsigned short* VTp = VT + (size_t)bh * HD_ * T_;
    const int b = bh >> 4, h = bh & 15;

    const int tid  = threadIdx.x;
    const int lane = tid & 63;
    const int w    = tid >> 6;
    const int g    = lane >> 4;
    const int c    = lane & 15;
    const float SC = 0.18033688011112042f;   // (1/sqrt(64)) * log2(e)

    // Staging constants for this thread (two 16B segments per half-tile):
    // seg i covers LDS bytes L = (i*256 + tid)*16 of the 8KB half.
    int srowK[2], scolK[2];
    #pragma unroll
    for (int i = 0; i < 2; ++i) {
        const int L = (i * 256 + tid) * 16;
        srowK[i] = L >> 7;                                   // 0..63
        scolK[i] = (L & 127) ^ ((srowK[i] & 3) << 5);        // pre-swizzled src col (bytes)
    }

    for (int hf = 0; hf < 2; ++hf) {
        const int qt = hf ? (31 - pr) : pr;
        const int qw = qt * 64 + w * 16;
        const int nt = qt + 1;          // 64-key tiles; last is diagonal

        // Q as B-operand frags, pre-scaled (log2 domain)
        bf16x8 qf[2];
        #pragma unroll
        for (int dk = 0; dk < 2; ++dk) {
            bf16x8 t = *(const bf16x8*)(Qp + (size_t)(qw + c) * HD_ + dk * 32 + g * 8);
            #pragma unroll
            for (int j = 0; j < 8; ++j)
                t[j] = (short)f2bf(bf2f((unsigned short)t[j]) * SC);
            qf[dk] = t;
        }

        float m_l = -1e30f, l_l = 0.f;
        f32x4 oacc[4] = {};

        for (int ti = 0; ti < nt; ++ti) {
            const int tb = ti << 6;
            const bool last = (ti == nt - 1);

            // ---- stage K (8KB) + V^T (8KB), linear dest, pre-swizzled src
            #pragma unroll
            for (int i = 0; i < 2; ++i) {
                const int L = (i * 256 + tid) * 16;
                gl_lds16(Kp + (size_t)(tb + srowK[i]) * HD_ + (scolK[i] >> 1),
                         Ks + (L >> 1));
                gl_lds16(VTp + (size_t)srowK[i] * T_ + tb + (scolK[i] >> 1),
                         Vs + (L >> 1));
            }
            __syncthreads();

            // ---- QK^T (swapped): sA (keys tb..tb+31), sB (tb+32..tb+63)
            f32x4 sA[2] = {}, sB[2] = {};
            #pragma unroll
            for (int ni = 0; ni < 2; ++ni)
                #pragma unroll
                for (int dk = 0; dk < 2; ++dk) {
                    const int rA = ni * 16 + c;
                    const int rB = 32 + ni * 16 + c;
                    const bf16x8 kA = *(const bf16x8*)((const char*)Ks
                        + rA * 128 + ((dk * 64 + g * 16) ^ ((c & 3) << 5)));
                    const bf16x8 kB = *(const bf16x8*)((const char*)Ks
                        + rB * 128 + ((dk * 64 + g * 16) ^ ((c & 3) << 5)));
                    sA[ni] = mfma16(kA, qf[dk], sA[ni]);
                    sB[ni] = mfma16(kB, qf[dk], sB[ni]);
                }

            // ---- mask (diagonal tile only)
            if (last) {
                #pragma unroll
                for (int ni = 0; ni < 2; ++ni)
                    #pragma unroll
                    for (int r = 0; r < 4; ++r) {
                        const int kA = tb + ni * 16 + g * 4 + r;
                        sA[ni][r] = (kA      <= qw + c) ? sA[ni][r] : -1e30f;
                        sB[ni][r] = (kA + 32 <= qw + c) ? sB[ni][r] : -1e30f;
                    }
            }

            // ---- online softmax (per-lane over 16 vals + 2 shuffles)
            float pmax = sA[0][0];
            #pragma unroll
            for (int ni = 0; ni < 2; ++ni)
                #pragma unroll
                for (int r = 0; r < 4; ++r) {
                    pmax = fmaxf(pmax, sA[ni][r]);
                    pmax = fmaxf(pmax, sB[ni][r]);
                }
            pmax = fmaxf(pmax, __shfl_xor(pmax, 16));
            pmax = fmaxf(pmax, __shfl_xor(pmax, 32));

            const float mn = fmaxf(m_l, pmax);
            const float al = exp2_fast(m_l - mn);
            m_l = mn;

            float rs = 0.f;
            #pragma unroll
            for (int ni = 0; ni < 2; ++ni)
                #pragma unroll
                for (int r = 0; r < 4; ++r) {
                    const float eA = exp2_fast(sA[ni][r] - mn);
                    const float eB = exp2_fast(sB[ni][r] - mn);
                    sA[ni][r] = eA; sB[ni][r] = eB;
                    rs += eA + eB;
                }
            rs += __shfl_xor(rs, 16);
            rs += __shfl_xor(rs, 32);
            l_l = l_l * al + rs;

            // ---- P transpose to PV A-fragments
            const bf16x8 pfA = ptrans(sA[0], sA[1], lane, g, c);
            const bf16x8 pfB = ptrans(sB[0], sB[1], lane, g, c);

            // ---- rescale + PV (swapped): oacc rows = d, col = q = c
            #pragma unroll
            for (int dn = 0; dn < 4; ++dn) {
                const int row = dn * 16 + c;
                const bf16x8 vA = *(const bf16x8*)((const char*)Vs
                    + row * 128 + ((g * 16)      ^ ((c & 3) << 5)));
                const bf16x8 vB = *(const bf16x8*)((const char*)Vs
                    + row * 128 + ((64 + g * 16) ^ ((c & 3) << 5)));
                #pragma unroll
                for (int r = 0; r < 4; ++r)
                    oacc[dn][r] *= al;
                oacc[dn] = mfma16(vA, pfA, oacc[dn]);
                oacc[dn] = mfma16(vB, pfB, oacc[dn]);
            }
            __syncthreads();
        }

        // ---- epilogue: O[q = qw+c][d = dn*16 + g*4 + r]
        const float li = 1.f / l_l;
        const size_t rowoff = (size_t)(b * T_ + qw + c) * D_ + h * 64;
        #pragma unroll
        for (int dn = 0; dn < 4; ++dn) {
            const unsigned int u0 = (unsigned int)f2bf(oacc[dn][0] * li)
                                  | ((unsigned int)f2bf(oacc[dn][1] * li) << 16);
            const unsigned int u1 = (unsigned int)f2bf(oacc[dn][2] * li)
                                  | ((unsigned int)f2bf(oacc[dn][3] * li) << 16);
            uint2 st; st.x = u0; st.y = u1;
            *(uint2*)(Y + rowoff + dn * 16 + g * 4) = st;
        }
    }
}

// ---------------------------------------------------------------------------
// Output projection:  out = Y @ Wp^T + bp.  Y bf16[8192,1024]; out fp32.
// ---------------------------------------------------------------------------
__global__ __launch_bounds__(256, 2)
void proj_kernel(const unsigned short* __restrict__ Yin,
                 const unsigned short* __restrict__ Wp,
                 const float* __restrict__ bp,
                 float* __restrict__ Out)
{
    __shared__ unsigned short As[128 * 64];
    __shared__ unsigned short Bs[128 * 64];

    const int m0 = blockIdx.x * 128;
    const int n0 = blockIdx.y * 128;
    const int tid  = threadIdx.x;
    const int lane = tid & 63;
    const int wv   = tid >> 6;
    const int wr   = (wv >> 1) * 64;
    const int wc   = (wv & 1) * 64;
    const int g    = lane >> 4;
    const int c    = lane & 15;

    f32x4 acc[4][4] = {};

    for (int k0 = 0; k0 < D_; k0 += 64) {
        #pragma unroll
        for (int i = 0; i < 4; ++i) {
            const int flat = i * 2048 + tid * 8;
            const int row = flat >> 6, col = flat & 63;
            gl_lds16(Yin + (size_t)(m0 + row) * D_ + k0 + col, As + flat);
            gl_lds16(Wp  + (size_t)(n0 + row) * D_ + k0 + col, Bs + flat);
        }
        __syncthreads();
        #pragma unroll
        for (int kk = 0; kk < 64; kk += 32) {
            bf16x8 af[4], bg[4];
            #pragma unroll
            for (int mi = 0; mi < 4; ++mi)
                af[mi] = *(const bf16x8*)(As + (wr + mi * 16 + c) * 64 + kk + g * 8);
            #pragma unroll
            for (int ni = 0; ni < 4; ++ni)
                bg[ni] = *(const bf16x8*)(Bs + (wc + ni * 16 + c) * 64 + kk + g * 8);
            #pragma unroll
            for (int mi = 0; mi < 4; ++mi)
                #pragma unroll
                for (int ni = 0; ni < 4; ++ni)
                    acc[mi][ni] = mfma16(af[mi], bg[ni], acc[mi][ni]);
        }
        __syncthreads();
    }

    #pragma unroll
    for (int mi = 0; mi < 4; ++mi) {
        #pragma unroll
        for (int ni = 0; ni < 4; ++ni) {
            const int n = n0 + wc + ni * 16 + c;
            const float bb = bp[n];
            #pragma unroll
            for (int r = 0; r < 4; ++r) {
                const int m = m0 + wr + mi * 16 + g * 4 + r;
                Out[(size_t)m * D_ + n] = acc[mi][ni][r] + bb;
            }
        }
    }
}

// ---------------------------------------------------------------------------
extern "C" void kernel_launch(void* const* d_in, const int* in_sizes, int n_in,
                              void* d_out, int out_size, void* d_ws, size_t ws_size,
                              hipStream_t stream) {
    const float* x  = (const float*)d_in[0];
    const float* Wq = (const float*)d_in[1];
    const float* Wk = (const float*)d_in[2];
    const float* Wv = (const float*)d_in[3];
    const float* Wp = (const float*)d_in[4];
    const float* bp = (const float*)d_in[5];
    float* out = (float*)d_out;

    const size_t SZ  = (size_t)M_ * D_;      // 8388608
    const size_t WSZ = (size_t)D_ * D_;      // 1048576
    unsigned short* ws = (unsigned short*)d_ws;
    unsigned short* XB  = ws;                 // also Y after qkv
    unsigned short* WQB = XB  + SZ;
    unsigned short* WKB = WQB + WSZ;
    unsigned short* WVB = WKB + WSZ;
    unsigned short* WPB = WVB + WSZ;
    unsigned short* Qw  = WPB + WSZ;
    unsigned short* Kw  = Qw + SZ;
    unsigned short* Vw  = Kw + SZ;            // V^T [B,H,HD,T]
    unsigned short* Yw  = XB;                 // overlay: x_bf16 dead after qkv

    dim3 blk(256);
    cvt_kernel <<<dim3(SZ / 1024),     blk, 0, stream>>>(x, XB);
    cvtw_kernel<<<dim3(WSZ / 1024, 4), blk, 0, stream>>>(Wq, Wk, Wv, Wp, WQB, WKB, WVB, WPB);

    qkv_kernel <<<dim3(M_ / 128, 24), blk, 0, stream>>>(XB, WQB, WKB, WVB, Qw, Kw, Vw);
    attn_kernel<<<dim3(B_ * H_, 16), blk, 0, stream>>>(Qw, Kw, Vw, Yw);
    proj_kernel<<<dim3(M_ / 128, D_ / 128), blk, 0, stream>>>(Yw, WPB, bp, out);
}